// Round 10
// baseline (201.208 us; speedup 1.0000x reference)
//
#include <hip/hip_runtime.h>

#define IMG_SIZE 256
#define NPIX (IMG_SIZE * IMG_SIZE)
#define KSEL 5
#define BS 8
#define LL 64
#define LUSED 63          // row l=63's top-k is discarded by the roll — never compute it
#define NTHREADS 256
#define SPLIT 4           // blocks per (b,l) row
#define CHUNK (NPIX / SPLIT)      // 16384 pixels per block
#define NBLKS (BS * LUSED * SPLIT)        // 2016
#define QCAP 320          // per-wave candidate queue; 4*QCAP*8 == NTHREADS*KSEL*8
#define SENTK 0xFFFFFFFFFFFFFFFFULL
#define FMAGIC 0xF1A6C0DE5EED0000ULL      // flag = FMAGIC | blk (low 16 bits free)

typedef unsigned long long ull;

// Branchless sorted-insert: loc[] ascending; bubble key in, evict the max.
// Static indices only -> stays in VGPRs; no divergence.
__device__ __forceinline__ void sort_insert(ull loc[KSEL], ull key) {
    #pragma unroll
    for (int j = 0; j < KSEL; ++j) {
        const ull a = loc[j];
        const bool lt = key < a;
        loc[j] = lt ? key : a;
        key    = lt ? a : key;
    }
}

// Merge two ascending 5-lists, keep smallest 5 into a.
__device__ __forceinline__ void merge5(ull* a, const ull* b) {
    ull out[KSEL];
    int ia = 0, ib = 0;
    #pragma unroll
    for (int j = 0; j < KSEL; ++j) {
        const ull va = a[ia], vb = b[ib];
        const bool ta = va <= vb;
        out[j] = ta ? va : vb;
        ia += ta ? 1 : 0;
        ib += ta ? 0 : 1;
    }
    #pragma unroll
    for (int j = 0; j < KSEL; ++j) a[j] = out[j];
}

// Single source of truth for the SSD: match numpy f32 exactly — no FMA
// contraction, ((d0^2+d1^2)+d2^2). Bootstrap keys and steady-path gate both
// use THIS function, so gate-s and key-s are bit-identical.
__device__ __forceinline__ float
pix_s(float r0, float r1, float r2, float c0, float c1, float c2) {
    float d0 = __fsub_rn(r0, c0);
    float d1 = __fsub_rn(r1, c1);
    float d2 = __fsub_rn(r2, c2);
    return __fadd_rn(__fadd_rn(__fmul_rn(d0, d0), __fmul_rn(d1, d1)), __fmul_rn(d2, d2));
}

__device__ __forceinline__ ull
pix_key(float r0, float r1, float r2, float c0, float c1, float c2, int pix) {
    // s >= 0 (sum of squares) -> uint bit order == float order; low bits = pixel
    // index gives jax top_k's lower-index-first tie-break.
    const float s = pix_s(r0, r1, r2, c0, c1, c2);
    return ((ull)__float_as_uint(s) << 32) | (unsigned int)pix;
}

// One block per (b,l,split). Verified R9 body (89.5us): bootstrap 1024 px ->
// block-exact threshold -> gate-to-memory steady loop (9-op s test, rare LDS
// queue push) -> drain -> verified merge tree. NEW here: the finalize kernel
// is FUSED as a tail run by block 0 after a flag barrier, removing one
// dispatch (~10us launch gap). Protocol (R5 lesson — tiny dirty footprint):
//   producer: write 40B keys; __syncthreads (drains stores); t0: threadfence
//             (XCD L2 writeback) + release-store flags[blk] = FMAGIC|blk.
//   consumer (block 0): acquire-poll all flags, threadfence, run the
//             byte-identical finalize body.
// Deadlock-free at ANY occupancy: producers never wait; the one consumer
// waits only on producers. Poison-safety: a poisoned qword equaling
// FMAGIC|blk is ~2016/2^64; if ws is ever NOT re-poisoned, stale flags come
// with stale-but-bit-identical keys (deterministic), so early reads are
// still correct.
__global__ __launch_bounds__(NTHREADS, 8)
void topk_kernel(const float* __restrict__ preds,
                 const float* __restrict__ imgs,
                 ull* __restrict__ keys_out,
                 ull* __restrict__ flags,
                 float* __restrict__ out) {
    const int blk = blockIdx.x;
    const int split = blk & (SPLIT - 1);
    const int row = blk / SPLIT;         // 0 .. BS*LUSED-1
    const int b = row / LUSED;
    const int l = row % LUSED;
    const int bid = b * LL + l;          // storage row (l < 63)
    const int t = threadIdx.x;
    const int wave = t >> 6;
    const int lane = t & 63;

    __shared__ union ShMem {
        ull sk[NTHREADS * KSEL];         // 10240 B: merge scratch
        ull qq[4][QCAP];                 // 10240 B: per-wave candidate queues
        float red[NTHREADS];             // finalize tail reduction
    } shm;
    __shared__ unsigned wcnt[4];
    __shared__ unsigned thrsh;

    if (t < 4) wcnt[t] = 0u;

    // Scrambled pooled indexing: flat i = l*bs + b; position from preds[i//L, i%L].
    const int i = l * BS + b;
    const int pb = i >> 6;
    const int pl = i & 63;
    const float px = preds[pb * (LL * 8) + pl * 8 + 0];
    const float py = preds[pb * (LL * 8) + pl * 8 + 1];

    // grid_sample nearest, align_corners=False, zeros padding.
    const float cx = __fsub_rn(__fmul_rn(px, 256.0f), 0.5f);
    const float cy = __fsub_rn(__fmul_rn(py, 256.0f), 0.5f);
    const int ix = (int)rintf(cx);       // round half to even == jnp.rint
    const int iy = (int)rintf(cy);
    const bool valid = (ix >= 0) && (ix < IMG_SIZE) && (iy >= 0) && (iy < IMG_SIZE);
    const int ixc = min(max(ix, 0), IMG_SIZE - 1);
    const int iyc = min(max(iy, 0), IMG_SIZE - 1);
    const float vmul = valid ? 1.0f : 0.0f;

    const float* imgb = imgs + (size_t)b * 3 * NPIX;
    const float c0 = imgb[0 * NPIX + iyc * IMG_SIZE + ixc] * vmul;
    const float c1 = imgb[1 * NPIX + iyc * IMG_SIZE + ixc] * vmul;
    const float c2 = imgb[2 * NPIX + iyc * IMG_SIZE + ixc] * vmul;

    const float4* p0 = (const float4*)(imgb + 0 * NPIX);
    const float4* p1 = (const float4*)(imgb + 1 * NPIX);
    const float4* p2 = (const float4*)(imgb + 2 * NPIX);

    ull loc[KSEL];
    #pragma unroll
    for (int j = 0; j < KSEL; ++j) loc[j] = SENTK;

    const int v0 = split * (CHUNK / 4);

    // ---- Bootstrap: iteration 0 (1024 pixels), unconditional inserts ----
    {
        const int v = v0 + t;
        const float4 r0 = p0[v];
        const float4 r1 = p1[v];
        const float4 r2 = p2[v];
        const int base = v * 4;
        sort_insert(loc, pix_key(r0.x, r1.x, r2.x, c0, c1, c2, base + 0));
        sort_insert(loc, pix_key(r0.y, r1.y, r2.y, c0, c1, c2, base + 1));
        sort_insert(loc, pix_key(r0.z, r1.z, r2.z, c0, c1, c2, base + 2));
        sort_insert(loc, pix_key(r0.w, r1.w, r2.w, c0, c1, c2, base + 3));
    }

    // Block-exact bootstrap threshold via the verified merge5 tree.
    #pragma unroll
    for (int j = 0; j < KSEL; ++j) shm.sk[t * KSEL + j] = loc[j];
    __syncthreads();
    for (int s = NTHREADS / 2; s > 0; s >>= 1) {
        if (t < s) {
            ull a[KSEL], bb[KSEL];
            #pragma unroll
            for (int j = 0; j < KSEL; ++j) { a[j] = shm.sk[t * KSEL + j]; bb[j] = shm.sk[(t + s) * KSEL + j]; }
            merge5(a, bb);
            #pragma unroll
            for (int j = 0; j < KSEL; ++j) shm.sk[t * KSEL + j] = a[j];
        }
        __syncthreads();
    }
    if (t == 0) thrsh = (unsigned)(shm.sk[KSEL - 1] >> 32);   // bits of s5(bootstrap)
    __syncthreads();
    const unsigned thr = thrsh;          // register; sk contents now dead -> qq may reuse
    if (t < 4) wcnt[t] = 0u;             // (re-assert; qq region about to be used)
    __syncthreads();

    // ---- Steady loop: dense loads, 9-op s + gate, rare queue push ----
    #pragma unroll 2
    for (int it = 1; it < CHUNK / 4 / NTHREADS; ++it) {
        // Overflow safety (wave-uniform; never triggers on random data):
        // guarantee room for this iteration's max 256 pushes (wcnt <= 64 after).
        if (wcnt[wave] + NTHREADS > QCAP) {
            const unsigned n = wcnt[wave];
            for (unsigned o = lane; o < n; o += 64) sort_insert(loc, shm.qq[wave][o]);
            if (lane == 0) wcnt[wave] = 0u;   // per-wave LDS ops are in-order: reads precede
        }
        const int v = v0 + it * NTHREADS + t;
        const float4 r0 = p0[v];
        const float4 r1 = p1[v];
        const float4 r2 = p2[v];
        const int base = v * 4;

        const float sx = pix_s(r0.x, r1.x, r2.x, c0, c1, c2);
        const float sy = pix_s(r0.y, r1.y, r2.y, c0, c1, c2);
        const float sz = pix_s(r0.z, r1.z, r2.z, c0, c1, c2);
        const float sw = pix_s(r0.w, r1.w, r2.w, c0, c1, c2);

        if (__float_as_uint(sx) <= thr) {
            const unsigned pos = atomicAdd(&wcnt[wave], 1u);
            shm.qq[wave][pos] = ((ull)__float_as_uint(sx) << 32) | (unsigned)(base + 0);
        }
        if (__float_as_uint(sy) <= thr) {
            const unsigned pos = atomicAdd(&wcnt[wave], 1u);
            shm.qq[wave][pos] = ((ull)__float_as_uint(sy) << 32) | (unsigned)(base + 1);
        }
        if (__float_as_uint(sz) <= thr) {
            const unsigned pos = atomicAdd(&wcnt[wave], 1u);
            shm.qq[wave][pos] = ((ull)__float_as_uint(sz) << 32) | (unsigned)(base + 2);
        }
        if (__float_as_uint(sw) <= thr) {
            const unsigned pos = atomicAdd(&wcnt[wave], 1u);
            shm.qq[wave][pos] = ((ull)__float_as_uint(sw) << 32) | (unsigned)(base + 3);
        }
    }

    // ---- End drain: queue -> per-lane lists (each entry inserted once) ----
    {
        const unsigned n = wcnt[wave];
        for (unsigned o = lane; o < n; o += 64) sort_insert(loc, shm.qq[wave][o]);
    }

    // ---- Verified block merge (byte-identical tree) + key output ----
    __syncthreads();                     // all waves done draining before sk reuse
    #pragma unroll
    for (int j = 0; j < KSEL; ++j) shm.sk[t * KSEL + j] = loc[j];
    __syncthreads();
    for (int s = NTHREADS / 2; s > 0; s >>= 1) {
        if (t < s) {
            ull a[KSEL], bb[KSEL];
            #pragma unroll
            for (int j = 0; j < KSEL; ++j) { a[j] = shm.sk[t * KSEL + j]; bb[j] = shm.sk[(t + s) * KSEL + j]; }
            merge5(a, bb);
            #pragma unroll
            for (int j = 0; j < KSEL; ++j) shm.sk[t * KSEL + j] = a[j];
        }
        __syncthreads();
    }

    if (t < KSEL) {
        keys_out[((size_t)bid * SPLIT + split) * KSEL + t] = shm.sk[t];
    }

    // ---- Publish: syncthreads drained the key stores to L2; t0 fence
    //      writes back this XCD's L2, then release-store the flag. ----
    __syncthreads();
    if (t == 0) {
        __threadfence();
        __hip_atomic_store(&flags[blk], FMAGIC | (unsigned)blk,
                           __ATOMIC_RELEASE, __HIP_MEMORY_SCOPE_AGENT);
    }

    // ---- Fused finalize: block 0 waits for all flags, then runs the
    //      byte-identical epilogue (merge SPLIT lists / roll / min-dist / mean).
    if (blk == 0) {
        for (int f = t; f < NBLKS; f += NTHREADS) {
            const ull want = FMAGIC | (unsigned)f;
            while (__hip_atomic_load(&flags[f], __ATOMIC_ACQUIRE,
                                     __HIP_MEMORY_SCOPE_AGENT) != want)
                __builtin_amdgcn_s_sleep(8);
        }
        __syncthreads();
        __threadfence();                  // acquire all producers' keys

        float acc = 0.0f;
        for (int p = t; p < BS * LUSED; p += NTHREADS) {
            const int bb_ = p / LUSED;
            const int ll_ = p % LUSED + 1;            // loss rows: l = 1..63
            const float pxl = preds[bb_ * (LL * 8) + ll_ * 8 + 0];
            const float pyl = preds[bb_ * (LL * 8) + ll_ * 8 + 1];

            // tgt_down[:, l] = tgt[:, l-1]: merge the SPLIT sorted 5-lists.
            const int srow = bb_ * LL + (ll_ - 1);
            ull fl[KSEL];
            #pragma unroll
            for (int j = 0; j < KSEL; ++j) fl[j] = SENTK;
            #pragma unroll
            for (int s = 0; s < SPLIT; ++s) {
                #pragma unroll
                for (int k = 0; k < KSEL; ++k) {
                    sort_insert(fl, keys_out[((size_t)srow * SPLIT + s) * KSEL + k]);
                }
            }

            float best = 3.4028235e38f;
            #pragma unroll
            for (int k = 0; k < KSEL; ++k) {
                const int ixk = (int)(fl[k] & 0xFFFFFFFFULL);
                const float tx = (float)(ixk & 255) * (1.0f / 256.0f);   // exact /256
                const float ty = (float)(ixk >> 8) * (1.0f / 256.0f);
                const float dx = __fsub_rn(pxl, tx);
                const float dy = __fsub_rn(pyl, ty);
                const float dist = __fadd_rn(__fmul_rn(dx, dx), __fmul_rn(dy, dy));
                best = dist < best ? dist : best;
            }
            acc += best;
        }

        shm.red[t] = acc;
        __syncthreads();
        for (int s = NTHREADS / 2; s > 0; s >>= 1) {
            if (t < s) shm.red[t] += shm.red[t + s];
            __syncthreads();
        }
        if (t == 0) {
            out[0] = shm.red[0] / (float)(BS * (LL - 1));
        }
    }
}

// ---------------------------------------------------------------------------
// Fallback path (verified): two-kernel brute force. Used only if workspace is
// too small for keys+flags (needs 96 KB).
// ---------------------------------------------------------------------------
__global__ __launch_bounds__(NTHREADS)
void topk_fb_kernel(const float* __restrict__ preds,
                    const float* __restrict__ imgs,
                    ull* __restrict__ keys_out) {
    const int blk = blockIdx.x;
    const int split = blk & (SPLIT - 1);
    const int row = blk / SPLIT;
    const int b = row / LUSED;
    const int l = row % LUSED;
    const int bid = b * LL + l;
    const int t = threadIdx.x;

    const int i = l * BS + b;
    const int pb = i >> 6;
    const int pl = i & 63;
    const float px = preds[pb * (LL * 8) + pl * 8 + 0];
    const float py = preds[pb * (LL * 8) + pl * 8 + 1];

    const float cx = __fsub_rn(__fmul_rn(px, 256.0f), 0.5f);
    const float cy = __fsub_rn(__fmul_rn(py, 256.0f), 0.5f);
    const int ix = (int)rintf(cx);
    const int iy = (int)rintf(cy);
    const bool valid = (ix >= 0) && (ix < IMG_SIZE) && (iy >= 0) && (iy < IMG_SIZE);
    const int ixc = min(max(ix, 0), IMG_SIZE - 1);
    const int iyc = min(max(iy, 0), IMG_SIZE - 1);
    const float vmul = valid ? 1.0f : 0.0f;

    const float* imgb = imgs + (size_t)b * 3 * NPIX;
    const float c0 = imgb[0 * NPIX + iyc * IMG_SIZE + ixc] * vmul;
    const float c1 = imgb[1 * NPIX + iyc * IMG_SIZE + ixc] * vmul;
    const float c2 = imgb[2 * NPIX + iyc * IMG_SIZE + ixc] * vmul;

    const float4* p0 = (const float4*)(imgb + 0 * NPIX);
    const float4* p1 = (const float4*)(imgb + 1 * NPIX);
    const float4* p2 = (const float4*)(imgb + 2 * NPIX);

    ull loc[KSEL];
    #pragma unroll
    for (int j = 0; j < KSEL; ++j) loc[j] = SENTK;

    const int v0 = split * (CHUNK / 4);
    #pragma unroll 2
    for (int it = 0; it < CHUNK / 4 / NTHREADS; ++it) {
        const int v = v0 + it * NTHREADS + t;
        float4 r0 = p0[v];
        float4 r1 = p1[v];
        float4 r2 = p2[v];
        const int base = v * 4;
        sort_insert(loc, pix_key(r0.x, r1.x, r2.x, c0, c1, c2, base + 0));
        sort_insert(loc, pix_key(r0.y, r1.y, r2.y, c0, c1, c2, base + 1));
        sort_insert(loc, pix_key(r0.z, r1.z, r2.z, c0, c1, c2, base + 2));
        sort_insert(loc, pix_key(r0.w, r1.w, r2.w, c0, c1, c2, base + 3));
    }

    __shared__ ull sk[NTHREADS * KSEL];
    #pragma unroll
    for (int j = 0; j < KSEL; ++j) sk[t * KSEL + j] = loc[j];
    __syncthreads();

    for (int s = NTHREADS / 2; s > 0; s >>= 1) {
        if (t < s) {
            ull a[KSEL], bb[KSEL];
            #pragma unroll
            for (int j = 0; j < KSEL; ++j) { a[j] = sk[t * KSEL + j]; bb[j] = sk[(t + s) * KSEL + j]; }
            merge5(a, bb);
            #pragma unroll
            for (int j = 0; j < KSEL; ++j) sk[t * KSEL + j] = a[j];
        }
        __syncthreads();
    }

    if (t < KSEL) {
        keys_out[((size_t)bid * SPLIT + split) * KSEL + t] = sk[t];
    }
}

__global__ __launch_bounds__(NTHREADS)
void finalize_kernel(const float* __restrict__ preds,
                     const ull* __restrict__ keys,
                     float* __restrict__ out) {
    const int t = threadIdx.x;
    float acc = 0.0f;

    for (int p = t; p < BS * LUSED; p += NTHREADS) {
        const int b = p / LUSED;
        const int l = p % LUSED + 1;              // loss rows: l = 1..63
        const float px = preds[b * (LL * 8) + l * 8 + 0];
        const float py = preds[b * (LL * 8) + l * 8 + 1];

        const int srow = b * LL + (l - 1);
        ull loc[KSEL];
        #pragma unroll
        for (int j = 0; j < KSEL; ++j) loc[j] = SENTK;
        #pragma unroll
        for (int s = 0; s < SPLIT; ++s) {
            #pragma unroll
            for (int k = 0; k < KSEL; ++k) {
                sort_insert(loc, keys[((size_t)srow * SPLIT + s) * KSEL + k]);
            }
        }

        float best = 3.4028235e38f;
        #pragma unroll
        for (int k = 0; k < KSEL; ++k) {
            const int ixk = (int)(loc[k] & 0xFFFFFFFFULL);
            const float tx = (float)(ixk & 255) * (1.0f / 256.0f);
            const float ty = (float)(ixk >> 8) * (1.0f / 256.0f);
            const float dx = __fsub_rn(px, tx);
            const float dy = __fsub_rn(py, ty);
            const float dist = __fadd_rn(__fmul_rn(dx, dx), __fmul_rn(dy, dy));
            best = dist < best ? dist : best;
        }
        acc += best;
    }

    __shared__ float red[NTHREADS];
    red[t] = acc;
    __syncthreads();
    for (int s = NTHREADS / 2; s > 0; s >>= 1) {
        if (t < s) red[t] += red[t + s];
        __syncthreads();
    }
    if (t == 0) {
        out[0] = red[0] / (float)(BS * (LL - 1));
    }
}

extern "C" void kernel_launch(void* const* d_in, const int* in_sizes, int n_in,
                              void* d_out, int out_size, void* d_ws, size_t ws_size,
                              hipStream_t stream) {
    const float* preds = (const float*)d_in[0];   // (8, 64, 8) f32
    const float* imgs  = (const float*)d_in[1];   // (8, 3, 256, 256) f32
    float* out = (float*)d_out;                   // scalar f32

    const size_t KEYS_BYTES  = (size_t)BS * LL * SPLIT * KSEL * sizeof(ull);  // 80 KB
    const size_t FLAG_BYTES  = (size_t)NBLKS * sizeof(ull);                   // 16 KB

    if (ws_size >= KEYS_BYTES + FLAG_BYTES) {
        ull* keys  = (ull*)d_ws;
        ull* flags = (ull*)((char*)d_ws + KEYS_BYTES);
        topk_kernel<<<dim3(NBLKS), dim3(NTHREADS), 0, stream>>>(preds, imgs, keys, flags, out);
    } else {
        // Fallback: verified two-kernel path (needs only 80 KB workspace).
        ull* keys = (ull*)d_ws;
        topk_fb_kernel<<<dim3(NBLKS), dim3(NTHREADS), 0, stream>>>(preds, imgs, keys);
        finalize_kernel<<<dim3(1), dim3(NTHREADS), 0, stream>>>(preds, keys, out);
    }
}

// Round 11
// 104.201 us; speedup vs baseline: 1.9310x; 1.9310x over previous
//
#include <hip/hip_runtime.h>

#define IMG_SIZE 256
#define NPIX (IMG_SIZE * IMG_SIZE)
#define KSEL 5
#define BS 8
#define LL 64
#define LUSED 63          // row l=63's top-k is discarded by the roll — never compute it
#define NTHREADS 256
#define SPLIT 4           // blocks per (b,l) row
#define CHUNK (NPIX / SPLIT)      // 16384 pixels per block
#define NBLKS (BS * LUSED * SPLIT)        // 2016
#define QCAP 320          // per-wave candidate queue; 4*QCAP*8 == NTHREADS*KSEL*8
#define SENTK 0xFFFFFFFFFFFFFFFFULL

typedef unsigned long long ull;

// Branchless sorted-insert: loc[] ascending; bubble key in, evict the max.
// Static indices only -> stays in VGPRs; no divergence.
__device__ __forceinline__ void sort_insert(ull loc[KSEL], ull key) {
    #pragma unroll
    for (int j = 0; j < KSEL; ++j) {
        const ull a = loc[j];
        const bool lt = key < a;
        loc[j] = lt ? key : a;
        key    = lt ? a : key;
    }
}

// Merge two ascending 5-lists, keep smallest 5 into a.
__device__ __forceinline__ void merge5(ull* a, const ull* b) {
    ull out[KSEL];
    int ia = 0, ib = 0;
    #pragma unroll
    for (int j = 0; j < KSEL; ++j) {
        const ull va = a[ia], vb = b[ib];
        const bool ta = va <= vb;
        out[j] = ta ? va : vb;
        ia += ta ? 1 : 0;
        ib += ta ? 0 : 1;
    }
    #pragma unroll
    for (int j = 0; j < KSEL; ++j) a[j] = out[j];
}

// Single source of truth for the SSD: match numpy f32 exactly — no FMA
// contraction, ((d0^2+d1^2)+d2^2). Bootstrap keys and steady-path gate both
// use THIS function, so gate-s and key-s are bit-identical.
__device__ __forceinline__ float
pix_s(float r0, float r1, float r2, float c0, float c1, float c2) {
    float d0 = __fsub_rn(r0, c0);
    float d1 = __fsub_rn(r1, c1);
    float d2 = __fsub_rn(r2, c2);
    return __fadd_rn(__fadd_rn(__fmul_rn(d0, d0), __fmul_rn(d1, d1)), __fmul_rn(d2, d2));
}

__device__ __forceinline__ ull
pix_key(float r0, float r1, float r2, float c0, float c1, float c2, int pix) {
    // s >= 0 (sum of squares) -> uint bit order == float order; low bits = pixel
    // index gives jax top_k's lower-index-first tie-break.
    const float s = pix_s(r0, r1, r2, c0, c1, c2);
    return ((ull)__float_as_uint(s) << 32) | (unsigned int)pix;
}

// One block per (b,l,split) — verified R9 body (89.5us): bootstrap 1024 px ->
// block-exact threshold (merge5 tree) -> gate-to-memory steady loop (9-op s
// test vs register thr, rare LDS-queue push) -> drain -> verified merge tree.
// R10 lesson: NO intra-kernel cross-block sync (agent-scope polling = L2
// transaction storm, 151us). Back to two dispatches.
// NEW here (T1, XCD swizzle): decode b = blk & 7 so, under the measured
// round-robin blockIdx%8 -> XCD mapping, ALL 252 blocks of image b run on one
// XCD. Working set per XCD drops 6.3MB (> 4MiB L2, thrashes to L3) -> 786KB
// (L2-resident): steady-loop loads become L2 hits. Pure index remap — if the
// dispatch mapping differs it only affects speed, never correctness.
// Exactness (unchanged from R9):
//   thr = 5th-smallest s over the bootstrap subset >= s5_chunk;
//   admit iff bits(s) <= thr => every true top-5 key is in bootstrap ∪ queue;
//   each pixel enters exactly once => bit-identical top-5.
__global__ __launch_bounds__(NTHREADS, 8)
void topk_kernel(const float* __restrict__ preds,
                 const float* __restrict__ imgs,
                 ull* __restrict__ keys_out) {
    const int blk = blockIdx.x;
    const int b = blk & 7;               // XCD-aligned image id (blockIdx%8 ~ XCD)
    const int w = blk >> 3;              // 0 .. 251 within image
    const int l = w >> 2;                // 0 .. 62
    const int split = w & 3;
    const int bid = b * LL + l;          // storage row (l < 63)
    const int t = threadIdx.x;
    const int wave = t >> 6;
    const int lane = t & 63;

    __shared__ union ShMem {
        ull sk[NTHREADS * KSEL];         // 10240 B: merge scratch
        ull qq[4][QCAP];                 // 10240 B: per-wave candidate queues
    } shm;
    __shared__ unsigned wcnt[4];
    __shared__ unsigned thrsh;

    if (t < 4) wcnt[t] = 0u;

    // Scrambled pooled indexing: flat i = l*bs + b; position from preds[i//L, i%L].
    const int i = l * BS + b;
    const int pb = i >> 6;
    const int pl = i & 63;
    const float px = preds[pb * (LL * 8) + pl * 8 + 0];
    const float py = preds[pb * (LL * 8) + pl * 8 + 1];

    // grid_sample nearest, align_corners=False, zeros padding.
    const float cx = __fsub_rn(__fmul_rn(px, 256.0f), 0.5f);
    const float cy = __fsub_rn(__fmul_rn(py, 256.0f), 0.5f);
    const int ix = (int)rintf(cx);       // round half to even == jnp.rint
    const int iy = (int)rintf(cy);
    const bool valid = (ix >= 0) && (ix < IMG_SIZE) && (iy >= 0) && (iy < IMG_SIZE);
    const int ixc = min(max(ix, 0), IMG_SIZE - 1);
    const int iyc = min(max(iy, 0), IMG_SIZE - 1);
    const float vmul = valid ? 1.0f : 0.0f;

    const float* imgb = imgs + (size_t)b * 3 * NPIX;
    const float c0 = imgb[0 * NPIX + iyc * IMG_SIZE + ixc] * vmul;
    const float c1 = imgb[1 * NPIX + iyc * IMG_SIZE + ixc] * vmul;
    const float c2 = imgb[2 * NPIX + iyc * IMG_SIZE + ixc] * vmul;

    const float4* p0 = (const float4*)(imgb + 0 * NPIX);
    const float4* p1 = (const float4*)(imgb + 1 * NPIX);
    const float4* p2 = (const float4*)(imgb + 2 * NPIX);

    ull loc[KSEL];
    #pragma unroll
    for (int j = 0; j < KSEL; ++j) loc[j] = SENTK;

    const int v0 = split * (CHUNK / 4);

    // ---- Bootstrap: iteration 0 (1024 pixels), unconditional inserts ----
    {
        const int v = v0 + t;
        const float4 r0 = p0[v];
        const float4 r1 = p1[v];
        const float4 r2 = p2[v];
        const int base = v * 4;
        sort_insert(loc, pix_key(r0.x, r1.x, r2.x, c0, c1, c2, base + 0));
        sort_insert(loc, pix_key(r0.y, r1.y, r2.y, c0, c1, c2, base + 1));
        sort_insert(loc, pix_key(r0.z, r1.z, r2.z, c0, c1, c2, base + 2));
        sort_insert(loc, pix_key(r0.w, r1.w, r2.w, c0, c1, c2, base + 3));
    }

    // Block-exact bootstrap threshold via the verified merge5 tree.
    #pragma unroll
    for (int j = 0; j < KSEL; ++j) shm.sk[t * KSEL + j] = loc[j];
    __syncthreads();
    for (int s = NTHREADS / 2; s > 0; s >>= 1) {
        if (t < s) {
            ull a[KSEL], bb[KSEL];
            #pragma unroll
            for (int j = 0; j < KSEL; ++j) { a[j] = shm.sk[t * KSEL + j]; bb[j] = shm.sk[(t + s) * KSEL + j]; }
            merge5(a, bb);
            #pragma unroll
            for (int j = 0; j < KSEL; ++j) shm.sk[t * KSEL + j] = a[j];
        }
        __syncthreads();
    }
    if (t == 0) thrsh = (unsigned)(shm.sk[KSEL - 1] >> 32);   // bits of s5(bootstrap)
    __syncthreads();
    const unsigned thr = thrsh;          // register; sk contents now dead -> qq may reuse
    if (t < 4) wcnt[t] = 0u;             // (re-assert; qq region about to be used)
    __syncthreads();

    // ---- Steady loop: dense loads, 9-op s + gate, rare queue push ----
    #pragma unroll 2
    for (int it = 1; it < CHUNK / 4 / NTHREADS; ++it) {
        // Overflow safety (wave-uniform; never triggers on random data):
        // guarantee room for this iteration's max 256 pushes (wcnt <= 64 after).
        if (wcnt[wave] + NTHREADS > QCAP) {
            const unsigned n = wcnt[wave];
            for (unsigned o = lane; o < n; o += 64) sort_insert(loc, shm.qq[wave][o]);
            if (lane == 0) wcnt[wave] = 0u;   // per-wave LDS ops are in-order: reads precede
        }
        const int v = v0 + it * NTHREADS + t;
        const float4 r0 = p0[v];
        const float4 r1 = p1[v];
        const float4 r2 = p2[v];
        const int base = v * 4;

        const float sx = pix_s(r0.x, r1.x, r2.x, c0, c1, c2);
        const float sy = pix_s(r0.y, r1.y, r2.y, c0, c1, c2);
        const float sz = pix_s(r0.z, r1.z, r2.z, c0, c1, c2);
        const float sw = pix_s(r0.w, r1.w, r2.w, c0, c1, c2);

        if (__float_as_uint(sx) <= thr) {
            const unsigned pos = atomicAdd(&wcnt[wave], 1u);
            shm.qq[wave][pos] = ((ull)__float_as_uint(sx) << 32) | (unsigned)(base + 0);
        }
        if (__float_as_uint(sy) <= thr) {
            const unsigned pos = atomicAdd(&wcnt[wave], 1u);
            shm.qq[wave][pos] = ((ull)__float_as_uint(sy) << 32) | (unsigned)(base + 1);
        }
        if (__float_as_uint(sz) <= thr) {
            const unsigned pos = atomicAdd(&wcnt[wave], 1u);
            shm.qq[wave][pos] = ((ull)__float_as_uint(sz) << 32) | (unsigned)(base + 2);
        }
        if (__float_as_uint(sw) <= thr) {
            const unsigned pos = atomicAdd(&wcnt[wave], 1u);
            shm.qq[wave][pos] = ((ull)__float_as_uint(sw) << 32) | (unsigned)(base + 3);
        }
    }

    // ---- End drain: queue -> per-lane lists (each entry inserted once) ----
    {
        const unsigned n = wcnt[wave];
        for (unsigned o = lane; o < n; o += 64) sort_insert(loc, shm.qq[wave][o]);
    }

    // ---- Verified block merge (byte-identical tree) + key output ----
    __syncthreads();                     // all waves done draining before sk reuse
    #pragma unroll
    for (int j = 0; j < KSEL; ++j) shm.sk[t * KSEL + j] = loc[j];
    __syncthreads();
    for (int s = NTHREADS / 2; s > 0; s >>= 1) {
        if (t < s) {
            ull a[KSEL], bb[KSEL];
            #pragma unroll
            for (int j = 0; j < KSEL; ++j) { a[j] = shm.sk[t * KSEL + j]; bb[j] = shm.sk[(t + s) * KSEL + j]; }
            merge5(a, bb);
            #pragma unroll
            for (int j = 0; j < KSEL; ++j) shm.sk[t * KSEL + j] = a[j];
        }
        __syncthreads();
    }

    if (t < KSEL) {
        keys_out[((size_t)bid * SPLIT + split) * KSEL + t] = shm.sk[t];
    }
}

// Epilogue (verified, unchanged): merge the SPLIT partial top-5s per row, roll
// along L, min positional distance over the 5 selected pixels, mean.
__global__ __launch_bounds__(NTHREADS)
void finalize_kernel(const float* __restrict__ preds,
                     const ull* __restrict__ keys,
                     float* __restrict__ out) {
    const int t = threadIdx.x;
    float acc = 0.0f;

    for (int p = t; p < BS * LUSED; p += NTHREADS) {
        const int b = p / LUSED;
        const int l = p % LUSED + 1;              // loss rows: l = 1..63
        const float px = preds[b * (LL * 8) + l * 8 + 0];
        const float py = preds[b * (LL * 8) + l * 8 + 1];

        // tgt_down[:, l] = tgt[:, l-1]: merge the SPLIT sorted 5-lists of row l-1.
        const int srow = b * LL + (l - 1);
        ull loc[KSEL];
        #pragma unroll
        for (int j = 0; j < KSEL; ++j) loc[j] = SENTK;
        #pragma unroll
        for (int s = 0; s < SPLIT; ++s) {
            #pragma unroll
            for (int k = 0; k < KSEL; ++k) {
                sort_insert(loc, keys[((size_t)srow * SPLIT + s) * KSEL + k]);
            }
        }

        float best = 3.4028235e38f;
        #pragma unroll
        for (int k = 0; k < KSEL; ++k) {
            const int ixk = (int)(loc[k] & 0xFFFFFFFFULL);
            const float tx = (float)(ixk & 255) * (1.0f / 256.0f);   // exact /256
            const float ty = (float)(ixk >> 8) * (1.0f / 256.0f);
            const float dx = __fsub_rn(px, tx);
            const float dy = __fsub_rn(py, ty);
            const float dist = __fadd_rn(__fmul_rn(dx, dx), __fmul_rn(dy, dy));
            best = dist < best ? dist : best;
        }
        acc += best;
    }

    __shared__ float red[NTHREADS];
    red[t] = acc;
    __syncthreads();
    for (int s = NTHREADS / 2; s > 0; s >>= 1) {
        if (t < s) red[t] += red[t + s];
        __syncthreads();
    }
    if (t == 0) {
        out[0] = red[0] / (float)(BS * (LL - 1));
    }
}

extern "C" void kernel_launch(void* const* d_in, const int* in_sizes, int n_in,
                              void* d_out, int out_size, void* d_ws, size_t ws_size,
                              hipStream_t stream) {
    const float* preds = (const float*)d_in[0];   // (8, 64, 8) f32
    const float* imgs  = (const float*)d_in[1];   // (8, 3, 256, 256) f32
    float* out = (float*)d_out;                   // scalar f32
    ull* keys = (ull*)d_ws;                       // 512 * SPLIT * 5 u64 = 80 KB

    topk_kernel<<<dim3(NBLKS), dim3(NTHREADS), 0, stream>>>(preds, imgs, keys);
    finalize_kernel<<<dim3(1), dim3(NTHREADS), 0, stream>>>(preds, keys, out);
}